// Round 5
// baseline (598.390 us; speedup 1.0000x reference)
//
#include <hip/hip_runtime.h>
#include <hip/hip_bf16.h>

#define N_TRAIN 200000
#define DIMS    64
#define NQ      1024
#define KSEL    32
#define NCLS    10

#define QB      128     // queries per gemm block / per wave (8 tiles of 16)
#define NQT     8       // NQ/QB
#define CHUNKS  64      // candidate groups (fallback: n-chunks)
#define CHROWS  3125    // N_TRAIN / CHUNKS (fallback)
#define CMAX    96      // candidate cap per (query, group)
#define MAXC    4096    // merge candidate cap per query
#define SAMPLES 8192    // threshold sample rows (rows 0..8191)
#define SCH     256     // fallback: sample rows per MODE1 block
#define NXB     12500   // k_x2 grid

#define CB2     512     // k_dist MODE0 chunks
#define CHROWS2 391     // ceil(N_TRAIN/CB2)

typedef float f32x4 __attribute__((ext_vector_type(4)));
typedef short bf16x8 __attribute__((ext_vector_type(8)));

__device__ __forceinline__ unsigned fmap(float f) {
    unsigned u = __float_as_uint(f);
    return u ^ ((u >> 31) ? 0xFFFFFFFFu : 0x80000000u);
}
__device__ __forceinline__ float funmap(unsigned m) {
    unsigned u = m ^ ((m >> 31) ? 0x80000000u : 0xFFFFFFFFu);
    return __uint_as_float(u);
}
__device__ __forceinline__ unsigned short f2bf(float f) {   // RNE f32->bf16 bits
    unsigned u = __float_as_uint(f);
    unsigned r = u + 0x7FFFu + ((u >> 16) & 1u);
    return (unsigned short)(r >> 16);
}
__device__ __forceinline__ bf16x8 pack8(float4 a, float4 b) {
    bf16x8 r;
    r[0] = (short)f2bf(a.x); r[1] = (short)f2bf(a.y);
    r[2] = (short)f2bf(a.z); r[3] = (short)f2bf(a.w);
    r[4] = (short)f2bf(b.x); r[5] = (short)f2bf(b.y);
    r[6] = (short)f2bf(b.z); r[7] = (short)f2bf(b.w);
    return r;
}

// ---------------------------------- x2 = ||x||^2 ; per-block max (NO atomics)
__global__ __launch_bounds__(256) void k_x2(const float* __restrict__ X,
                                            float* __restrict__ x2,
                                            float* __restrict__ bmax) {
    int T = blockIdx.x * 256 + threadIdx.x;      // 16 threads per row
    int row = T >> 4;
    int l16 = T & 15;
    float4 v = ((const float4*)X)[(long)row * 16 + l16];
    float p = v.x * v.x + v.y * v.y + v.z * v.z + v.w * v.w;
    p += __shfl_xor(p, 1);
    p += __shfl_xor(p, 2);
    p += __shfl_xor(p, 4);
    p += __shfl_xor(p, 8);
    if (l16 == 0) x2[row] = p;
    float m = p;
    m = fmaxf(m, __shfl_xor(m, 16));
    m = fmaxf(m, __shfl_xor(m, 32));
    __shared__ float wm[4];
    if ((threadIdx.x & 63) == 0) wm[threadIdx.x >> 6] = m;
    __syncthreads();
    if (threadIdx.x == 0)
        bmax[blockIdx.x] = fmaxf(fmaxf(wm[0], wm[1]), fmaxf(wm[2], wm[3]));
}

__global__ __launch_bounds__(256) void k_max(const float* __restrict__ bmax,
                                             float* __restrict__ x2maxf) {
    float m = -1e30f;
    for (int i = threadIdx.x; i < NXB; i += 256) m = fmaxf(m, bmax[i]);
#pragma unroll
    for (int d = 1; d < 64; d <<= 1) m = fmaxf(m, __shfl_xor(m, d));
    __shared__ float wm[4];
    if ((threadIdx.x & 63) == 0) wm[threadIdx.x >> 6] = m;
    __syncthreads();
    if (threadIdx.x == 0)
        *x2maxf = fmaxf(fmaxf(wm[0], wm[1]), fmaxf(wm[2], wm[3]));
}

// ---------------------------------- f32 -> bf16 copies (RNE)
__global__ __launch_bounds__(256) void k_cvt(const float* __restrict__ src,
                                             short* __restrict__ dst) {
    long c = (long)blockIdx.x * 256 + threadIdx.x;   // 8 elems per thread
    const float4* xp = (const float4*)(src + c * 8);
    float4 a = xp[0], b = xp[1];
    *(bf16x8*)(dst + c * 8) = pack8(a, b);
}

// ================================================================ k_dist
// Barrier-free, LDS-free MFMA distance pass over bf16 Xb/Qb.
// Block = 4 independent waves; wave w handles query tile qt = qtg*4+w (128 q).
// MODE 0: filter rows [cb*CHROWS2, ...) vs widened thresholds -> cand pools
// MODE 1: write u16 mapped keys for sample rows [(bid>>1)*128, +128)
template<int MODE>
__global__ __launch_bounds__(256, 4) void k_dist(
    const short* __restrict__ Xb, const short* __restrict__ Qb,
    const float* __restrict__ x2, const float* __restrict__ tqw,
    int* __restrict__ cnt_g, unsigned* __restrict__ cand,
    unsigned short* __restrict__ keys) {
    int bid = blockIdx.x;
    int w = threadIdx.x >> 6;
    int lane = threadIdx.x & 63;
    int qt = ((bid & 1) << 2) + w;           // 0..7
    int cb = bid >> 1;
    int lr = lane & 15;                      // train-row-in-group / A-row
    int lk = lane >> 4;                      // k-chunk 0..3

    // A fragments: 128 queries, 64 VGPR
    bf16x8 afr[8][2];
#pragma unroll
    for (int qi = 0; qi < 8; qi++) {
        const short* qp = Qb + (long)((qt << 7) + (qi << 4) + lr) * 64 + (lk << 3);
        afr[qi][0] = *(const bf16x8*)qp;
        afr[qi][1] = *(const bf16x8*)(qp + 32);
    }

    float htq[8];
    if (MODE == 0) {
#pragma unroll
        for (int qi = 0; qi < 8; qi++) {
            const float4 t4 = *(const float4*)(tqw + (qt << 7) + (qi << 4) + (lk << 2));
            htq[qi] = 0.5f * fmaxf(fmaxf(t4.x, t4.y), fmaxf(t4.z, t4.w));
        }
    }

    int r0 = MODE ? (cb << 7) : cb * CHROWS2;
    int rowEnd = MODE ? (r0 + 128) : min(r0 + CHROWS2, N_TRAIN);
    int g = cb >> 3;   // candidate group (MODE 0)

    for (int base = r0; base < rowEnd; base += 16) {
        int row = base + lr;
        bool valid = row < rowEnd;
        int rowc = valid ? row : (rowEnd - 1);
        const short* xp = Xb + (long)rowc * 64 + (lk << 3);
        bf16x8 b0 = *(const bf16x8*)xp;
        bf16x8 b1 = *(const bf16x8*)(xp + 32);
        float x2c = valid ? x2[rowc] : 1e30f;
        float hx = 0.5f * x2c;

#pragma unroll
        for (int qi = 0; qi < 8; qi++) {
            f32x4 acc = {0.f, 0.f, 0.f, 0.f};
            acc = __builtin_amdgcn_mfma_f32_16x16x32_bf16(afr[qi][0], b0, acc, 0, 0, 0);
            acc = __builtin_amdgcn_mfma_f32_16x16x32_bf16(afr[qi][1], b1, acc, 0, 0, 0);
            if (MODE == 1) {
#pragma unroll
                for (int r = 0; r < 4; r++) {
                    float key = x2c - 2.f * acc[r];
                    int qg = (qt << 7) + (qi << 4) + (lk << 2) + r;
                    keys[(long)qg * SAMPLES + row] = (unsigned short)(fmap(key) >> 16);
                }
            } else {
                float mx = fmaxf(fmaxf(acc[0], acc[1]), fmaxf(acc[2], acc[3]));
                if (mx + htq[qi] >= hx) {       // sound quick reject (rare pass)
                    const float4 t4 = *(const float4*)(tqw + (qt << 7) + (qi << 4) + (lk << 2));
                    float tq4[4] = {t4.x, t4.y, t4.z, t4.w};
#pragma unroll
                    for (int r = 0; r < 4; r++) {
                        if (acc[r] + 0.5f * tq4[r] >= hx) {
                            int qg = (qt << 7) + (qi << 4) + (lk << 2) + r;
                            int slot = atomicAdd(&cnt_g[qg * CHUNKS + g], 1);
                            if (slot < CMAX)
                                cand[((long)qg * CHUNKS + g) * CMAX + slot] = (unsigned)row;
                        }
                    }
                }
            }
        }
    }
}

// ================================================================ fallback
// R4's proven LDS-staged kernel (used when workspace too small for Xb/Qb).
template<int MODE>
__global__ __launch_bounds__(256, 2) void k_gemm(
    const float* __restrict__ Xf,
    const float* __restrict__ Qm, const float* __restrict__ x2,
    const float* __restrict__ tqw, int* __restrict__ cnt_g,
    unsigned* __restrict__ cand, unsigned short* __restrict__ keys) {
    int bid = blockIdx.x;
    int qt = bid & (NQT - 1);
    int cb = bid >> 3;
    int r0 = cb * (MODE ? SCH : CHROWS);
    int rcnt = MODE ? SCH : CHROWS;

    int tid = threadIdx.x;
    int lane = tid & 63;
    int w = tid >> 6;
    int lr = lane & 15;
    int lk = lane >> 4;

    __shared__ short xs[256 * 64];
    __shared__ float x2s[256];
    __shared__ float tqh[QB];

    if (MODE == 0 && tid < QB) tqh[tid] = 0.5f * tqw[(qt << 7) + tid];
    __syncthreads();

    float htqmax[8];
    if (MODE == 0) {
#pragma unroll
        for (int qi = 0; qi < 8; qi++) {
            int b = (qi << 4) + (lk << 2);
            htqmax[qi] = fmaxf(fmaxf(tqh[b], tqh[b + 1]), fmaxf(tqh[b + 2], tqh[b + 3]));
        }
    }

    bf16x8 afr[8][2];
#pragma unroll
    for (int qi = 0; qi < 8; qi++) {
        int qrow = (qt << 7) + (qi << 4) + lr;
        const float4* qp0 = (const float4*)(Qm + (long)qrow * 64 + lk * 8);
        const float4* qp1 = (const float4*)(Qm + (long)qrow * 64 + 32 + lk * 8);
        afr[qi][0] = pack8(qp0[0], qp0[1]);
        afr[qi][1] = pack8(qp1[0], qp1[1]);
    }

    for (int sb = 0; sb < rcnt; sb += 256) {
        int nv = min(256, rcnt - sb);
        __syncthreads();
#pragma unroll
        for (int m = 0; m < 8; m++) {
            int c = tid + 256 * m;
            int row = c >> 3, ch = c & 7;
            bf16x8 v = {0, 0, 0, 0, 0, 0, 0, 0};
            if (row < nv) {
                long gr = (long)(r0 + sb + row);
                const float4* xp = (const float4*)(Xf + gr * 64 + ch * 8);
                v = pack8(xp[0], xp[1]);
            }
            *(bf16x8*)(xs + row * 64 + ((ch ^ (row & 7)) * 8)) = v;
        }
        x2s[tid] = (tid < nv) ? x2[r0 + sb + tid] : 1e30f;
        __syncthreads();

#pragma unroll
        for (int j = 0; j < 4; j++) {
            int nr = (w << 6) + (j << 4) + lr;
            int sw = nr & 7;
            bf16x8 b0 = *(const bf16x8*)(xs + nr * 64 + ((lk ^ sw) * 8));
            bf16x8 b1 = *(const bf16x8*)(xs + nr * 64 + (((4 + lk) ^ sw) * 8));
            float x2v = x2s[nr];
            float hx = 0.5f * x2v;
#pragma unroll
            for (int qi = 0; qi < 8; qi++) {
                f32x4 acc = {0.f, 0.f, 0.f, 0.f};
                acc = __builtin_amdgcn_mfma_f32_16x16x32_bf16(afr[qi][0], b0, acc, 0, 0, 0);
                acc = __builtin_amdgcn_mfma_f32_16x16x32_bf16(afr[qi][1], b1, acc, 0, 0, 0);
                if (MODE == 1) {
                    int sg = r0 + sb + nr;
#pragma unroll
                    for (int r = 0; r < 4; r++) {
                        float key = x2v - 2.f * acc[r];
                        int qg = (qt << 7) + (qi << 4) + (lk << 2) + r;
                        keys[(long)qg * SAMPLES + sg] = (unsigned short)(fmap(key) >> 16);
                    }
                } else {
                    float mx = fmaxf(fmaxf(acc[0], acc[1]), fmaxf(acc[2], acc[3]));
                    if (mx + htqmax[qi] >= hx) {
#pragma unroll
                        for (int r = 0; r < 4; r++) {
                            if (acc[r] + tqh[(qi << 4) + (lk << 2) + r] >= hx) {
                                int qg = (qt << 7) + (qi << 4) + (lk << 2) + r;
                                int ng = r0 + sb + nr;
                                int slot = atomicAdd(&cnt_g[qg * CHUNKS + cb], 1);
                                if (slot < CMAX)
                                    cand[((long)qg * CHUNKS + cb) * CMAX + slot] = (unsigned)ng;
                            }
                        }
                    }
                }
            }
        }
    }
}

// ------------------------------------------------ 32nd-smallest sample key -> threshold
__global__ __launch_bounds__(256) void k_sel(const unsigned short* __restrict__ keys,
                                             const float* __restrict__ Qm,
                                             const float* __restrict__ x2maxf,
                                             float* __restrict__ tqw,
                                             float* __restrict__ q2g) {
    int q = blockIdx.x, tid = threadIdx.x;
    unsigned short mk[32];
#pragma unroll
    for (int m = 0; m < 32; m++) mk[m] = keys[(long)q * SAMPLES + tid + 256 * m];
    __shared__ float q2s_;
    __shared__ int cnt;
    if (tid < 64) {
        float v = Qm[(long)q * 64 + tid];
        float p = v * v;
#pragma unroll
        for (int d = 1; d < 64; d <<= 1) p += __shfl_xor(p, d);
        if (tid == 0) q2s_ = p;
    }
    unsigned lo = 0, hi = 65535;
    for (int it = 0; it < 16; ++it) {
        __syncthreads();
        if (tid == 0) cnt = 0;
        __syncthreads();
        unsigned mid = (lo + hi) >> 1;
        int c = 0;
#pragma unroll
        for (int m = 0; m < 32; m++) c += (mk[m] <= mid) ? 1 : 0;
#pragma unroll
        for (int d = 1; d < 64; d <<= 1) c += __shfl_xor(c, d);
        if ((tid & 63) == 0) atomicAdd(&cnt, c);
        __syncthreads();
        if (cnt >= KSEL) hi = mid; else lo = mid + 1;
    }
    if (tid == 0) {
        unsigned vv = hi + 2u; if (vv > 65535u) vv = 65535u;
        float t = funmap(vv << 16);
        float x2m = *x2maxf;
        float q2 = q2s_;
        tqw[q] = t + 0.0314f * sqrtf(q2 * x2m) + 0.2f;
        q2g[q] = q2;
    }
}

// ------------------------------------------------ exact re-rank + vote + argmax
__global__ __launch_bounds__(256) void k_merge(const float* __restrict__ Qm,
                                               const float* __restrict__ X,
                                               const float* __restrict__ x2,
                                               const int* __restrict__ labels,
                                               const int* __restrict__ cnt_g,
                                               const unsigned* __restrict__ cand,
                                               const float* __restrict__ q2g,
                                               int* __restrict__ out) {
    int q = blockIdx.x, tid = threadIdx.x;
    __shared__ int idxL[MAXC];
    __shared__ float keyL[MAXC];
    __shared__ int labL[MAXC];
    __shared__ float qs[64];
    __shared__ int cnts[CHUNKS];
    __shared__ int tot, cnt, nw, nt;
    __shared__ float wKey[34];
    __shared__ int wLab[34];
    __shared__ int tIdx[64];
    __shared__ int tLab[64];

    if (tid == 0) { tot = 0; nw = 0; nt = 0; }
    if (tid < CHUNKS) cnts[tid] = min(cnt_g[q * CHUNKS + tid], CMAX);
    if (tid < 64) qs[tid] = Qm[(long)q * 64 + tid];
    for (int i = tid; i < MAXC; i += 256) { keyL[i] = 1e30f; idxL[i] = 0x7FFFFFFF; labL[i] = 0; }
    __syncthreads();

#pragma unroll
    for (int m = 0; m < 24; m++) {
        int g = tid + 256 * m;
        int c = g / CMAX, s = g - c * CMAX;
        if (s < cnts[c]) {
            int p = atomicAdd(&tot, 1);
            if (p < MAXC) idxL[p] = (int)cand[((long)q * CHUNKS + c) * CMAX + s];
        }
    }
    __syncthreads();
    int T = min(tot, MAXC);
    for (int i = tid; i < T; i += 256) {
        int ix = idxL[i];
        const float4* xr = (const float4*)(X + (long)ix * 64);
        const float4* qr = (const float4*)qs;
        float dot = 0.f;
#pragma unroll
        for (int k4 = 0; k4 < 16; k4++) {
            float4 xv = xr[k4];
            float4 qv = qr[k4];
            dot += qv.x * xv.x + qv.y * xv.y + qv.z * xv.z + qv.w * xv.w;
        }
        keyL[i] = x2[ix] - 2.f * dot;
        labL[i] = labels[ix];
    }
    __syncthreads();

    unsigned uk[16];
#pragma unroll
    for (int m = 0; m < 16; m++) uk[m] = fmap(keyL[tid + 256 * m]);

    unsigned lo = 0u, hi = 0xFFFFFFFFu;
    for (int it = 0; it < 32; ++it) {
        __syncthreads();
        if (tid == 0) cnt = 0;
        __syncthreads();
        unsigned mid = lo + ((hi - lo) >> 1);
        int c = 0;
#pragma unroll
        for (int m = 0; m < 16; m++) c += (uk[m] <= mid) ? 1 : 0;
#pragma unroll
        for (int d = 1; d < 64; d <<= 1) c += __shfl_xor(c, d);
        if ((tid & 63) == 0) atomicAdd(&cnt, c);
        __syncthreads();
        if (cnt >= KSEL) hi = mid; else lo = mid + 1;
    }
    unsigned T32 = hi;

#pragma unroll
    for (int m = 0; m < 16; m++) {
        int g = tid + 256 * m;
        if (uk[m] < T32) {
            int p = atomicAdd(&nw, 1);
            if (p < 34) { wKey[p] = keyL[g]; wLab[p] = labL[g]; }
        } else if (uk[m] == T32) {
            int p = atomicAdd(&nt, 1);
            if (p < 64) { tIdx[p] = idxL[g]; tLab[p] = labL[g]; }
        }
    }
    __syncthreads();

    if (tid == 0) {
        float q2v = q2g[q];
        float votes[NCLS] = {0.f, 0.f, 0.f, 0.f, 0.f, 0.f, 0.f, 0.f, 0.f, 0.f};
        int NW = min(nw, 32);
        for (int i = 0; i < NW; i++) {
            float dist = q2v + wKey[i];
            if (dist < 0.f) dist = 0.f;
            if (dist == 0.f) dist = 0.1f;
            votes[wLab[i]] += 1.f / dist;
        }
        int need = KSEL - NW;
        int NT = min(nt, 64);
        float tkey = funmap(T32);
        float dist = q2v + tkey;
        if (dist < 0.f) dist = 0.f;
        if (dist == 0.f) dist = 0.1f;
        float twgt = 1.f / dist;
        for (int t = 0; t < need && t < NT; t++) {
            int best = -1, bi = 0x7FFFFFFF;
            for (int u = 0; u < NT; u++)
                if (tIdx[u] < bi) { bi = tIdx[u]; best = u; }
            if (best < 0) break;
            votes[tLab[best]] += twgt;
            tIdx[best] = 0x7FFFFFFF;
        }
        float bv = votes[0];
        int bc = 0;
#pragma unroll
        for (int c = 1; c < NCLS; c++)
            if (votes[c] > bv) { bv = votes[c]; bc = c; }
        out[q] = bc;
    }
}

extern "C" void kernel_launch(void* const* d_in, const int* in_sizes, int n_in,
                              void* d_out, int out_size, void* d_ws, size_t ws_size,
                              hipStream_t stream) {
    const float* Qm = (const float*)d_in[0];
    const float* X = (const float*)d_in[1];
    const int* labels = (const int*)d_in[2];
    char* ws = (char*)d_ws;
    // ws layout:
    // [0,262144)           cnt_g  int[1024*64]
    // [262144,1062144)     x2     float[200000]
    // [1062144,1066240)    tqw    float[1024]
    // [1066240,1070336)    q2g    float[1024]
    // [1070336,1070340)    x2maxf float
    // [1070400,1120400)    bmax   float[12500]
    // [1120512,26286336)   cand u32[1024*64*96] ALIASED WITH keys u16[1024*8192]
    // -- extended (Xb path only) --
    // [26286336,51886336)  Xb bf16[200000*64]
    // [51886336,52017408)  Qb bf16[1024*64]
    int* cnt_g = (int*)(ws + 0);
    float* x2 = (float*)(ws + 262144);
    float* tqw = (float*)(ws + 1062144);
    float* q2g = (float*)(ws + 1066240);
    float* x2maxf = (float*)(ws + 1070336);
    float* bmax = (float*)(ws + 1070400);
    unsigned short* keys = (unsigned short*)(ws + 1120512);
    unsigned* cand = (unsigned*)(ws + 1120512);
    short* Xb = (short*)(ws + 26286336);
    short* Qb = (short*)(ws + 51886336);
    bool use_xb = ws_size >= 52017408ull;   // deterministic per harness
    int* out = (int*)d_out;

    hipMemsetAsync(cnt_g, 0, 262144, stream);
    k_x2<<<NXB, 256, 0, stream>>>(X, x2, bmax);
    k_max<<<1, 256, 0, stream>>>(bmax, x2maxf);
    if (use_xb) {
        k_cvt<<<6250, 256, 0, stream>>>(X, Xb);
        k_cvt<<<32, 256, 0, stream>>>(Qm, Qb);
        k_dist<1><<<2 * (SAMPLES / 128), 256, 0, stream>>>(Xb, Qb, x2, tqw, cnt_g, cand, keys);
        k_sel<<<NQ, 256, 0, stream>>>(keys, Qm, x2maxf, tqw, q2g);
        k_dist<0><<<2 * CB2, 256, 0, stream>>>(Xb, Qb, x2, tqw, cnt_g, cand, keys);
    } else {
        k_gemm<1><<<NQT * (SAMPLES / SCH), 256, 0, stream>>>(X, Qm, x2, tqw, cnt_g, cand, keys);
        k_sel<<<NQ, 256, 0, stream>>>(keys, Qm, x2maxf, tqw, q2g);
        k_gemm<0><<<NQT * CHUNKS, 256, 0, stream>>>(X, Qm, x2, tqw, cnt_g, cand, keys);
    }
    k_merge<<<NQ, 256, 0, stream>>>(Qm, X, x2, labels, cnt_g, cand, q2g, out);
}

// Round 6
// 355.065 us; speedup vs baseline: 1.6853x; 1.6853x over previous
//
#include <hip/hip_runtime.h>
#include <hip/hip_bf16.h>

#define N_TRAIN 200000
#define DIMS    64
#define NQ      1024
#define KSEL    32
#define NCLS    10

#define CHROWS2 391     // rows per k_dist<0> block; 512*391 >= 200000
#define NBLK0   512     // k_dist<0> grid
#define CMAX    96      // global pool cap per (g, q)
#define NG      64      // pool groups (g = bid>>3), 3128 rows per group
#define TOTC    4096    // merge candidate cap per query
#define MAXS    1536    // merge survivor cap per query
#define SAMPLES 8192
#define NPB     3125    // k_prep blocks

typedef float f32x4 __attribute__((ext_vector_type(4)));
typedef short bf16x8 __attribute__((ext_vector_type(8)));

__device__ __forceinline__ unsigned fmap(float f) {
    unsigned u = __float_as_uint(f);
    return u ^ ((u >> 31) ? 0xFFFFFFFFu : 0x80000000u);
}
__device__ __forceinline__ float funmap(unsigned m) {
    unsigned u = m ^ ((m >> 31) ? 0x80000000u : 0xFFFFFFFFu);
    return __uint_as_float(u);
}
__device__ __forceinline__ unsigned short f2bf(float f) {   // RNE f32->bf16 bits
    unsigned u = __float_as_uint(f);
    unsigned r = u + 0x7FFFu + ((u >> 16) & 1u);
    return (unsigned short)(r >> 16);
}
__device__ __forceinline__ bf16x8 pack8(float4 a, float4 b) {
    bf16x8 r;
    r[0] = (short)f2bf(a.x); r[1] = (short)f2bf(a.y);
    r[2] = (short)f2bf(a.z); r[3] = (short)f2bf(a.w);
    r[4] = (short)f2bf(b.x); r[5] = (short)f2bf(b.y);
    r[6] = (short)f2bf(b.z); r[7] = (short)f2bf(b.w);
    return r;
}

// ---------------- fused: x2 = ||x||^2, per-block max, X -> bf16 (one X read)
__global__ __launch_bounds__(512) void k_prep(const float* __restrict__ X,
                                              float* __restrict__ x2,
                                              float* __restrict__ bmax,
                                              short* __restrict__ Xb) {
    int T = blockIdx.x * 512 + threadIdx.x;   // 8 threads per row
    int row = T >> 3;
    int l8 = T & 7;
    const float4* xp = (const float4*)(X + (long)row * 64 + l8 * 8);
    float4 a = xp[0], b = xp[1];
    *(bf16x8*)(Xb + (long)row * 64 + l8 * 8) = pack8(a, b);
    float p = a.x * a.x + a.y * a.y + a.z * a.z + a.w * a.w +
              b.x * b.x + b.y * b.y + b.z * b.z + b.w * b.w;
    p += __shfl_xor(p, 1);
    p += __shfl_xor(p, 2);
    p += __shfl_xor(p, 4);        // all 8 lanes hold row sum
    if (l8 == 0) x2[row] = p;
    float m = p;
    m = fmaxf(m, __shfl_xor(m, 8));
    m = fmaxf(m, __shfl_xor(m, 16));
    m = fmaxf(m, __shfl_xor(m, 32));
    __shared__ float wm[8];
    if ((threadIdx.x & 63) == 0) wm[threadIdx.x >> 6] = m;
    __syncthreads();
    if (threadIdx.x == 0) {
        float r = wm[0];
#pragma unroll
        for (int i = 1; i < 8; i++) r = fmaxf(r, wm[i]);
        bmax[blockIdx.x] = r;
    }
}

__global__ __launch_bounds__(256) void k_max(const float* __restrict__ bmax,
                                             float* __restrict__ x2maxf) {
    float m = -1e30f;
    for (int i = threadIdx.x; i < NPB; i += 256) m = fmaxf(m, bmax[i]);
#pragma unroll
    for (int d = 1; d < 64; d <<= 1) m = fmaxf(m, __shfl_xor(m, d));
    __shared__ float wm[4];
    if ((threadIdx.x & 63) == 0) wm[threadIdx.x >> 6] = m;
    __syncthreads();
    if (threadIdx.x == 0)
        *x2maxf = fmaxf(fmaxf(wm[0], wm[1]), fmaxf(wm[2], wm[3]));
}

// ---------------- Q f32 -> bf16
__global__ __launch_bounds__(256) void k_cvt(const float* __restrict__ src,
                                             short* __restrict__ dst) {
    long c = (long)blockIdx.x * 256 + threadIdx.x;
    const float4* xp = (const float4*)(src + c * 8);
    float4 a = xp[0], b = xp[1];
    *(bf16x8*)(dst + c * 8) = pack8(a, b);
}

// ================================================================ k_dist
// 512 threads = 8 waves; wave w owns query tile w (128 queries, A-frags in reg).
// Block stages its row-chunk once into LDS (swizzled), all waves consume it.
// MODE 1: 64 blocks x 128 sample rows -> packed u16 keys (q-major).
// MODE 0: 512 blocks x 391 rows -> LDS-pooled candidate append, one flush.
template<int MODE>
__global__ __launch_bounds__(512, 4) void k_dist(
    const short* __restrict__ Xb, const short* __restrict__ Qb,
    const float* __restrict__ x2, const float* __restrict__ tqw,
    unsigned* __restrict__ cnt_g, unsigned* __restrict__ cand,
    unsigned short* __restrict__ keys) {
    int bid = blockIdx.x;
    int tid = threadIdx.x;
    int qt = tid >> 6;          // wave = query tile 0..7
    int lane = tid & 63;
    int lr = lane & 15;
    int lk = lane >> 4;

    __shared__ short xs[128 * 64];       // 16 KB, slot s of row r holds chunk s^(r&7)
    __shared__ float x2s[128];
    __shared__ unsigned lcnt[NQ];        // MODE0 only
    __shared__ unsigned lbuf[NQ * 8];    // MODE0 only

    int r0 = MODE ? (bid << 7) : bid * CHROWS2;
    int rowEnd = MODE ? (r0 + 128) : min(r0 + CHROWS2, N_TRAIN);
    int rcnt = rowEnd - r0;
    int g = MODE ? 0 : (bid >> 3);
    int gbase = g * (CHROWS2 * 8);       // 3128

    if (MODE == 0) { lcnt[tid] = 0u; lcnt[tid + 512] = 0u; }

    // A fragments: lane holds Q[qt*128+qi*16+lr][lk*8+j] per half
    bf16x8 afr[8][2];
#pragma unroll
    for (int qi = 0; qi < 8; qi++) {
        const short* qp = Qb + (long)((qt << 7) + (qi << 4) + lr) * 64 + (lk << 3);
        afr[qi][0] = *(const bf16x8*)qp;
        afr[qi][1] = *(const bf16x8*)(qp + 32);
    }
    float htq[8];
    if (MODE == 0) {
#pragma unroll
        for (int qi = 0; qi < 8; qi++) {
            float4 t4 = *(const float4*)(tqw + (qt << 7) + (qi << 4) + (lk << 2));
            htq[qi] = 0.5f * fmaxf(fmaxf(t4.x, t4.y), fmaxf(t4.z, t4.w));
        }
    }

    for (int sb = 0; sb < rcnt; sb += 128) {
        __syncthreads();   // previous compute done (also covers lcnt init)
#pragma unroll
        for (int k = 0; k < 2; k++) {
            int c = tid + (k << 9);             // 1024 16B chunks
            int r = c >> 3, sl = c & 7;
            bf16x8 v = *(const bf16x8*)(Xb + (long)(r0 + sb + r) * 64 + ((sl ^ (r & 7)) << 3));
            *(bf16x8*)(xs + r * 64 + (sl << 3)) = v;
        }
        if (tid < 128) x2s[tid] = x2[r0 + sb + tid];
        __syncthreads();

#pragma unroll
        for (int g16 = 0; g16 < 8; g16++) {
            int r = (g16 << 4) + lr;
            int grow = r0 + sb + r;
            bool valid = grow < rowEnd;
            int sw = r & 7;
            bf16x8 b0 = *(const bf16x8*)(xs + r * 64 + ((lk ^ sw) << 3));
            bf16x8 b1 = *(const bf16x8*)(xs + r * 64 + (((4 + lk) ^ sw) << 3));
            float x2c = x2s[r];
            float hx = 0.5f * x2c;
#pragma unroll
            for (int qi = 0; qi < 8; qi++) {
                f32x4 acc = {0.f, 0.f, 0.f, 0.f};
                acc = __builtin_amdgcn_mfma_f32_16x16x32_bf16(afr[qi][0], b0, acc, 0, 0, 0);
                acc = __builtin_amdgcn_mfma_f32_16x16x32_bf16(afr[qi][1], b1, acc, 0, 0, 0);
                if (MODE == 1) {
#pragma unroll
                    for (int r4 = 0; r4 < 4; r4++) {
                        unsigned k16 = fmap(x2c - 2.f * acc[r4]) >> 16;
                        unsigned o = (unsigned)__shfl_xor((int)k16, 1);
                        unsigned v2 = k16 | (o << 16);                 // rows lr,lr+1 (even lr)
                        unsigned p2 = (unsigned)__shfl_xor((int)v2, 2); // rows lr+2,lr+3
                        if ((lr & 3) == 0) {
                            int qg = (qt << 7) + (qi << 4) + (lk << 2) + r4;
                            *(uint2*)(&keys[(long)qg * SAMPLES + grow]) = make_uint2(v2, p2);
                        }
                    }
                } else {
                    float mx = fmaxf(fmaxf(acc[0], acc[1]), fmaxf(acc[2], acc[3]));
                    if (valid && mx + htq[qi] >= hx) {     // sound quick reject
                        float4 t4 = *(const float4*)(tqw + (qt << 7) + (qi << 4) + (lk << 2));
                        float tq4[4] = {t4.x, t4.y, t4.z, t4.w};
#pragma unroll
                        for (int r4 = 0; r4 < 4; r4++) {
                            if (acc[r4] + 0.5f * tq4[r4] >= hx) {
                                int qg = (qt << 7) + (qi << 4) + (lk << 2) + r4;
                                unsigned key16 = fmap(x2c - 2.f * acc[r4]) >> 16;
                                unsigned entry = (key16 << 12) | (unsigned)(grow - gbase);
                                unsigned sl2 = atomicAdd(&lcnt[qg], 1u);
                                if (sl2 < 8u) {
                                    lbuf[(qg << 3) + sl2] = entry;
                                } else {   // rare overflow: sound direct append
                                    unsigned gs = atomicAdd(&cnt_g[(g << 10) + qg], 1u);
                                    if (gs < CMAX)
                                        cand[((long)(g << 10) + qg) * CMAX + gs] = entry;
                                }
                            }
                        }
                    }
                }
            }
        }
    }

    if (MODE == 0) {   // bulk flush: one global atomic per (query, block)
        __syncthreads();
        for (int q = tid; q < NQ; q += 512) {
            unsigned lc = min(lcnt[q], 8u);
            if (lc) {
                unsigned base = atomicAdd(&cnt_g[(g << 10) + q], lc);
                for (unsigned i = 0; i < lc; i++) {
                    unsigned p = base + i;
                    if (p < CMAX) cand[((long)(g << 10) + q) * CMAX + p] = lbuf[(q << 3) + i];
                }
            }
        }
    }
}

// ---------------- 32nd-smallest sample key -> widened threshold
__global__ __launch_bounds__(256) void k_sel(const unsigned short* __restrict__ keys,
                                             const float* __restrict__ Qm,
                                             const float* __restrict__ x2maxf,
                                             float* __restrict__ tqw,
                                             float* __restrict__ q2g) {
    int q = blockIdx.x, tid = threadIdx.x;
    unsigned short mk[32];
#pragma unroll
    for (int m = 0; m < 32; m++) mk[m] = keys[(long)q * SAMPLES + tid + 256 * m];
    __shared__ float q2s_;
    __shared__ int cnt;
    if (tid < 64) {
        float v = Qm[(long)q * 64 + tid];
        float p = v * v;
#pragma unroll
        for (int d = 1; d < 64; d <<= 1) p += __shfl_xor(p, d);
        if (tid == 0) q2s_ = p;
    }
    unsigned lo = 0, hi = 65535;
    for (int it = 0; it < 16; ++it) {
        __syncthreads();
        if (tid == 0) cnt = 0;
        __syncthreads();
        unsigned mid = (lo + hi) >> 1;
        int c = 0;
#pragma unroll
        for (int m = 0; m < 32; m++) c += (mk[m] <= mid) ? 1 : 0;
#pragma unroll
        for (int d = 1; d < 64; d <<= 1) c += __shfl_xor(c, d);
        if ((tid & 63) == 0) atomicAdd(&cnt, c);
        __syncthreads();
        if (cnt >= KSEL) hi = mid; else lo = mid + 1;
    }
    if (tid == 0) {
        unsigned vv = hi + 2u; if (vv > 65535u) vv = 65535u;
        float t = funmap(vv << 16);
        float q2 = q2s_;
        tqw[q] = t + 0.0314f * sqrtf(q2 * (*x2maxf)) + 0.2f;
        q2g[q] = q2;
    }
}

// ---------------- approx-cut -> exact re-rank survivors -> vote -> argmax
__global__ __launch_bounds__(256) void k_merge(const float* __restrict__ Qm,
                                               const float* __restrict__ X,
                                               const float* __restrict__ x2,
                                               const int* __restrict__ labels,
                                               const unsigned* __restrict__ cnt_g,
                                               const unsigned* __restrict__ cand,
                                               const float* __restrict__ q2g,
                                               const float* __restrict__ x2maxf,
                                               int* __restrict__ out) {
    int q = blockIdx.x, tid = threadIdx.x;
    __shared__ unsigned short eK[TOTC];
    __shared__ int eR[TOTC];
    __shared__ int sR[MAXS];
    __shared__ float sKey[MAXS];
    __shared__ int sLab[MAXS];
    __shared__ float qs[64];
    __shared__ int cnts[NG];
    __shared__ int tot, cnt, ns, nw, nt;
    __shared__ unsigned cutS;
    __shared__ float wKey[34];
    __shared__ int wLab[34];
    __shared__ int tIdx[64];
    __shared__ int tLab[64];

    if (tid == 0) { tot = 0; ns = 0; nw = 0; nt = 0; }
    if (tid < NG) cnts[tid] = min((int)cnt_g[(tid << 10) + q], CMAX);
    if (tid < 64) qs[tid] = Qm[(long)q * 64 + tid];
    __syncthreads();

    // gather candidates
    for (int m = 0; m < 24; m++) {      // 64 * 96 = 6144
        int gi = tid + (m << 8);
        int gg = gi / CMAX, s = gi - gg * CMAX;
        if (s < cnts[gg]) {
            unsigned e = cand[((long)(gg << 10) + q) * CMAX + s];
            int p = atomicAdd(&tot, 1);
            if (p < TOTC) {
                eK[p] = (unsigned short)(e >> 12);
                eR[p] = gg * (CHROWS2 * 8) + (int)(e & 4095u);
            }
        }
    }
    __syncthreads();
    int T = min(tot, TOTC);

    // bisect approx u16 keys for the 32nd smallest
    unsigned short mk[16];
#pragma unroll
    for (int m = 0; m < 16; m++) { int i = tid + (m << 8); mk[m] = (i < T) ? eK[i] : (unsigned short)0xFFFFu; }
    unsigned lo = 0, hi = 65535;
    for (int it = 0; it < 16; ++it) {
        __syncthreads();
        if (tid == 0) cnt = 0;
        __syncthreads();
        unsigned mid = (lo + hi) >> 1;
        int c = 0;
#pragma unroll
        for (int m = 0; m < 16; m++) c += (mk[m] <= mid) ? 1 : 0;
#pragma unroll
        for (int d = 1; d < 64; d <<= 1) c += __shfl_xor(c, d);
        if ((tid & 63) == 0) atomicAdd(&cnt, c);
        __syncthreads();
        if (cnt >= KSEL) hi = mid; else lo = mid + 1;
    }
    float q2v = q2g[q];
    if (tid == 0) {
        unsigned vv = min(hi + 1u, 65535u);
        float tf = funmap(vv << 16);
        float err = 0.0314f * sqrtf(q2v * (*x2maxf)) + 0.3f;   // 2x bf16 key error + margin
        cutS = min((fmap(tf + err) >> 16) + 1u, 65535u);
    }
    __syncthreads();
    unsigned cut = cutS;
    for (int i = tid; i < T; i += 256)
        if ((unsigned)eK[i] <= cut) { int p = atomicAdd(&ns, 1); if (p < MAXS) sR[p] = eR[i]; }
    __syncthreads();
    int NS = min(ns, MAXS);

    // exact fp32 re-rank of survivors
    for (int i = tid; i < NS; i += 256) {
        int row = sR[i];
        const float4* xr = (const float4*)(X + (long)row * 64);
        const float4* qr = (const float4*)qs;
        float dot = 0.f;
#pragma unroll
        for (int k4 = 0; k4 < 16; k4++) {
            float4 xv = xr[k4], qv = qr[k4];
            dot += qv.x * xv.x + qv.y * xv.y + qv.z * xv.z + qv.w * xv.w;
        }
        sKey[i] = x2[row] - 2.f * dot;
        sLab[i] = labels[row];
    }
    __syncthreads();

    // exact 32nd smallest among survivors (32-step bisection)
    unsigned uk[6];
#pragma unroll
    for (int m = 0; m < 6; m++) { int i = tid + (m << 8); uk[m] = (i < NS) ? fmap(sKey[i]) : 0xFFFFFFFFu; }
    unsigned lo2 = 0u, hi2 = 0xFFFFFFFFu;
    for (int it = 0; it < 32; ++it) {
        __syncthreads();
        if (tid == 0) cnt = 0;
        __syncthreads();
        unsigned mid = lo2 + ((hi2 - lo2) >> 1);
        int c = 0;
#pragma unroll
        for (int m = 0; m < 6; m++) c += (uk[m] <= mid) ? 1 : 0;
#pragma unroll
        for (int d = 1; d < 64; d <<= 1) c += __shfl_xor(c, d);
        if ((tid & 63) == 0) atomicAdd(&cnt, c);
        __syncthreads();
        if (cnt >= KSEL) hi2 = mid; else lo2 = mid + 1;
    }
    unsigned T32 = hi2;   // count(<T32) <= 31, count(<=T32) >= 32

#pragma unroll
    for (int m = 0; m < 6; m++) {
        int i = tid + (m << 8);
        if (i < NS) {
            if (uk[m] < T32) {
                int p = atomicAdd(&nw, 1);
                if (p < 34) { wKey[p] = sKey[i]; wLab[p] = sLab[i]; }
            } else if (uk[m] == T32) {
                int p = atomicAdd(&nt, 1);
                if (p < 64) { tIdx[p] = sR[i]; tLab[p] = sLab[i]; }
            }
        }
    }
    __syncthreads();

    if (tid == 0) {
        float votes[NCLS] = {0.f, 0.f, 0.f, 0.f, 0.f, 0.f, 0.f, 0.f, 0.f, 0.f};
        int NW = min(nw, 32);
        for (int i = 0; i < NW; i++) {
            float dist = q2v + wKey[i];
            if (dist < 0.f) dist = 0.f;
            if (dist == 0.f) dist = 0.1f;
            votes[wLab[i]] += 1.f / dist;
        }
        int need = KSEL - NW;
        int NT = min(nt, 64);
        float tkey = funmap(T32);
        float dist = q2v + tkey;
        if (dist < 0.f) dist = 0.f;
        if (dist == 0.f) dist = 0.1f;
        float twgt = 1.f / dist;
        for (int t = 0; t < need && t < NT; t++) {   // ties: smallest index first
            int best = -1, bi = 0x7FFFFFFF;
            for (int u = 0; u < NT; u++)
                if (tIdx[u] < bi) { bi = tIdx[u]; best = u; }
            if (best < 0) break;
            votes[tLab[best]] += twgt;
            tIdx[best] = 0x7FFFFFFF;
        }
        float bv = votes[0];
        int bc = 0;
#pragma unroll
        for (int c = 1; c < NCLS; c++)
            if (votes[c] > bv) { bv = votes[c]; bc = c; }
        out[q] = bc;
    }
}

extern "C" void kernel_launch(void* const* d_in, const int* in_sizes, int n_in,
                              void* d_out, int out_size, void* d_ws, size_t ws_size,
                              hipStream_t stream) {
    const float* Qm = (const float*)d_in[0];
    const float* X = (const float*)d_in[1];
    const int* labels = (const int*)d_in[2];
    char* ws = (char*)d_ws;
    // ws layout (end = 51,979,840 B; R5 proved ws_size >= 52,017,408):
    // [0,262144)            cnt_g  u32[64*1024]       (g-major pools)
    // [262144,1062144)      x2     float[200000]
    // [1062144,1066240)     tqw    float[1024]
    // [1066240,1070336)     q2g    float[1024]
    // [1070336,1070340)     x2maxf float
    // [1070400,1082900)     bmax   float[3125]
    // [1082944,26248768)    cand u32[64*1024*96]  ALIASED WITH keys u16[1024*8192]
    // [26248768,51848768)   Xb bf16[200000*64]
    // [51848768,51979840)   Qb bf16[1024*64]
    unsigned* cnt_g = (unsigned*)(ws + 0);
    float* x2 = (float*)(ws + 262144);
    float* tqw = (float*)(ws + 1062144);
    float* q2g = (float*)(ws + 1066240);
    float* x2maxf = (float*)(ws + 1070336);
    float* bmax = (float*)(ws + 1070400);
    unsigned short* keys = (unsigned short*)(ws + 1082944);
    unsigned* cand = (unsigned*)(ws + 1082944);
    short* Xb = (short*)(ws + 26248768);
    short* Qb = (short*)(ws + 51848768);
    int* out = (int*)d_out;

    hipMemsetAsync(cnt_g, 0, 262144, stream);
    k_prep<<<NPB, 512, 0, stream>>>(X, x2, bmax, Xb);
    k_max<<<1, 256, 0, stream>>>(bmax, x2maxf);
    k_cvt<<<32, 256, 0, stream>>>(Qm, Qb);
    k_dist<1><<<SAMPLES / 128, 512, 0, stream>>>(Xb, Qb, x2, tqw, cnt_g, cand, keys);
    k_sel<<<NQ, 256, 0, stream>>>(keys, Qm, x2maxf, tqw, q2g);
    k_dist<0><<<NBLK0, 512, 0, stream>>>(Xb, Qb, x2, tqw, cnt_g, cand, keys);
    k_merge<<<NQ, 256, 0, stream>>>(Qm, X, x2, labels, cnt_g, cand, q2g, x2maxf, out);
}

// Round 7
// 302.799 us; speedup vs baseline: 1.9762x; 1.1726x over previous
//
#include <hip/hip_runtime.h>
#include <hip/hip_bf16.h>

#define N_TRAIN 200000
#define DIMS    64
#define NQ      1024
#define KSEL    32
#define NCLS    10

#define CHROWS2 391     // rows per k_dist<0> block; 512*391 >= 200000
#define NBLK0   512     // k_dist<0> grid
#define LCAP    8       // per-(block,query) pool cap
#define OVFCAP  256     // per-query overflow cap
#define TOTC    4096    // merge candidate cap per query
#define MAXS    1536    // merge survivor cap per query
#define SAMPLES 8192
#define NPB     3125    // k_prep blocks

typedef float f32x4 __attribute__((ext_vector_type(4)));
typedef short bf16x8 __attribute__((ext_vector_type(8)));

__device__ __forceinline__ unsigned fmap(float f) {
    unsigned u = __float_as_uint(f);
    return u ^ ((u >> 31) ? 0xFFFFFFFFu : 0x80000000u);
}
__device__ __forceinline__ float funmap(unsigned m) {
    unsigned u = m ^ ((m >> 31) ? 0x80000000u : 0xFFFFFFFFu);
    return __uint_as_float(u);
}
__device__ __forceinline__ unsigned short f2bf(float f) {   // RNE f32->bf16 bits
    unsigned u = __float_as_uint(f);
    unsigned r = u + 0x7FFFu + ((u >> 16) & 1u);
    return (unsigned short)(r >> 16);
}
__device__ __forceinline__ bf16x8 pack8(float4 a, float4 b) {
    bf16x8 r;
    r[0] = (short)f2bf(a.x); r[1] = (short)f2bf(a.y);
    r[2] = (short)f2bf(a.z); r[3] = (short)f2bf(a.w);
    r[4] = (short)f2bf(b.x); r[5] = (short)f2bf(b.y);
    r[6] = (short)f2bf(b.z); r[7] = (short)f2bf(b.w);
    return r;
}

// ---------------- fused: x2 = ||x||^2, per-block max, X -> bf16 (one X read)
__global__ __launch_bounds__(512) void k_prep(const float* __restrict__ X,
                                              float* __restrict__ x2,
                                              float* __restrict__ bmax,
                                              short* __restrict__ Xb) {
    int T = blockIdx.x * 512 + threadIdx.x;   // 8 threads per row
    int row = T >> 3;
    int l8 = T & 7;
    const float4* xp = (const float4*)(X + (long)row * 64 + l8 * 8);
    float4 a = xp[0], b = xp[1];
    *(bf16x8*)(Xb + (long)row * 64 + l8 * 8) = pack8(a, b);
    float p = a.x * a.x + a.y * a.y + a.z * a.z + a.w * a.w +
              b.x * b.x + b.y * b.y + b.z * b.z + b.w * b.w;
    p += __shfl_xor(p, 1);
    p += __shfl_xor(p, 2);
    p += __shfl_xor(p, 4);
    if (l8 == 0) x2[row] = p;
    float m = p;
    m = fmaxf(m, __shfl_xor(m, 8));
    m = fmaxf(m, __shfl_xor(m, 16));
    m = fmaxf(m, __shfl_xor(m, 32));
    __shared__ float wm[8];
    if ((threadIdx.x & 63) == 0) wm[threadIdx.x >> 6] = m;
    __syncthreads();
    if (threadIdx.x == 0) {
        float r = wm[0];
#pragma unroll
        for (int i = 1; i < 8; i++) r = fmaxf(r, wm[i]);
        bmax[blockIdx.x] = r;
    }
}

__global__ __launch_bounds__(256) void k_max(const float* __restrict__ bmax,
                                             float* __restrict__ x2maxf) {
    float m = -1e30f;
    for (int i = threadIdx.x; i < NPB; i += 256) m = fmaxf(m, bmax[i]);
#pragma unroll
    for (int d = 1; d < 64; d <<= 1) m = fmaxf(m, __shfl_xor(m, d));
    __shared__ float wm[4];
    if ((threadIdx.x & 63) == 0) wm[threadIdx.x >> 6] = m;
    __syncthreads();
    if (threadIdx.x == 0)
        *x2maxf = fmaxf(fmaxf(wm[0], wm[1]), fmaxf(wm[2], wm[3]));
}

// ---------------- Q f32 -> bf16
__global__ __launch_bounds__(256) void k_cvt(const float* __restrict__ src,
                                             short* __restrict__ dst) {
    long c = (long)blockIdx.x * 256 + threadIdx.x;
    const float4* xp = (const float4*)(src + c * 8);
    float4 a = xp[0], b = xp[1];
    *(bf16x8*)(dst + c * 8) = pack8(a, b);
}

// ================================================================ k_dist
// 512 threads = 8 waves; wave w owns query tile w (128 queries, A-frags in reg).
// Block stages its row-chunk once into LDS (swizzled), all waves consume it.
// MODE 1: 64 blocks x 128 sample rows -> packed u16 keys (q-major).
// MODE 0: 512 blocks x 391 rows -> block-exclusive LDS pools, coalesced flush.
template<int MODE>
__global__ __launch_bounds__(512) void k_dist(
    const short* __restrict__ Xb, const short* __restrict__ Qb,
    const float* __restrict__ x2, const float* __restrict__ tqw,
    unsigned* __restrict__ pcnt, unsigned* __restrict__ pool,
    unsigned* __restrict__ ovfcnt, uint2* __restrict__ ovf,
    unsigned short* __restrict__ keys) {
    int bid = blockIdx.x;
    int tid = threadIdx.x;
    int qt = tid >> 6;          // wave = query tile 0..7
    int lane = tid & 63;
    int lr = lane & 15;
    int lk = lane >> 4;

    __shared__ short xs[128 * 64];                      // 16 KB, swizzled
    __shared__ float x2s[128];
    __shared__ unsigned lcnt[MODE == 0 ? NQ : 1];       // MODE0 only
    __shared__ unsigned lbuf[MODE == 0 ? NQ * LCAP : 1];

    int r0 = MODE ? (bid << 7) : bid * CHROWS2;
    int rowEnd = MODE ? (r0 + 128) : min(r0 + CHROWS2, N_TRAIN);
    int rcnt = rowEnd - r0;

    if (MODE == 0) { lcnt[tid] = 0u; lcnt[tid + 512] = 0u; }

    // A fragments: lane holds Q[qt*128+qi*16+lr][lk*8+j] per half
    bf16x8 afr[8][2];
#pragma unroll
    for (int qi = 0; qi < 8; qi++) {
        const short* qp = Qb + (long)((qt << 7) + (qi << 4) + lr) * 64 + (lk << 3);
        afr[qi][0] = *(const bf16x8*)qp;
        afr[qi][1] = *(const bf16x8*)(qp + 32);
    }
    float htq[8];
    if (MODE == 0) {
#pragma unroll
        for (int qi = 0; qi < 8; qi++) {
            float4 t4 = *(const float4*)(tqw + (qt << 7) + (qi << 4) + (lk << 2));
            htq[qi] = 0.5f * fmaxf(fmaxf(t4.x, t4.y), fmaxf(t4.z, t4.w));
        }
    }

    for (int sb = 0; sb < rcnt; sb += 128) {
        __syncthreads();   // previous compute done (also covers lcnt init)
#pragma unroll
        for (int k = 0; k < 2; k++) {
            int c = tid + (k << 9);             // 1024 16B chunks
            int r = c >> 3, sl = c & 7;
            bf16x8 v = *(const bf16x8*)(Xb + (long)(r0 + sb + r) * 64 + ((sl ^ (r & 7)) << 3));
            *(bf16x8*)(xs + r * 64 + (sl << 3)) = v;
        }
        if (tid < 128) x2s[tid] = x2[r0 + sb + tid];
        __syncthreads();

#pragma unroll
        for (int g16 = 0; g16 < 8; g16++) {
            int r = (g16 << 4) + lr;
            int grow = r0 + sb + r;
            bool valid = grow < rowEnd;
            int sw = r & 7;
            bf16x8 b0 = *(const bf16x8*)(xs + r * 64 + ((lk ^ sw) << 3));
            bf16x8 b1 = *(const bf16x8*)(xs + r * 64 + (((4 + lk) ^ sw) << 3));
            float x2c = x2s[r];
            float hx = 0.5f * x2c;
#pragma unroll
            for (int qi = 0; qi < 8; qi++) {
                f32x4 acc = {0.f, 0.f, 0.f, 0.f};
                acc = __builtin_amdgcn_mfma_f32_16x16x32_bf16(afr[qi][0], b0, acc, 0, 0, 0);
                acc = __builtin_amdgcn_mfma_f32_16x16x32_bf16(afr[qi][1], b1, acc, 0, 0, 0);
                if (MODE == 1) {
#pragma unroll
                    for (int r4 = 0; r4 < 4; r4++) {
                        unsigned k16 = fmap(x2c - 2.f * acc[r4]) >> 16;
                        unsigned o = (unsigned)__shfl_xor((int)k16, 1);
                        unsigned v2 = k16 | (o << 16);                  // rows lr,lr+1
                        unsigned p2 = (unsigned)__shfl_xor((int)v2, 2); // rows lr+2,lr+3
                        if ((lr & 3) == 0) {
                            int qg = (qt << 7) + (qi << 4) + (lk << 2) + r4;
                            *(uint2*)(&keys[(long)qg * SAMPLES + grow]) = make_uint2(v2, p2);
                        }
                    }
                } else {
                    float mx = fmaxf(fmaxf(acc[0], acc[1]), fmaxf(acc[2], acc[3]));
                    if (valid && mx + htq[qi] >= hx) {     // sound quick reject
                        float4 t4 = *(const float4*)(tqw + (qt << 7) + (qi << 4) + (lk << 2));
                        float tq4[4] = {t4.x, t4.y, t4.z, t4.w};
#pragma unroll
                        for (int r4 = 0; r4 < 4; r4++) {
                            if (acc[r4] + 0.5f * tq4[r4] >= hx) {
                                int qg = (qt << 7) + (qi << 4) + (lk << 2) + r4;
                                unsigned key16 = fmap(x2c - 2.f * acc[r4]) >> 16;
                                unsigned slot = atomicAdd(&lcnt[qg], 1u);
                                if (slot < LCAP) {
                                    lbuf[qg * LCAP + slot] = (key16 << 9) | (unsigned)(grow - r0);
                                } else {   // rare overflow: per-query global pool
                                    unsigned o = atomicAdd(&ovfcnt[qg], 1u);
                                    if (o < OVFCAP)
                                        ovf[qg * OVFCAP + o] = make_uint2(key16, (unsigned)grow);
                                }
                            }
                        }
                    }
                }
            }
        }
    }

    if (MODE == 0) {   // coalesced flush: no atomics, dense 32B per (bid,q)
        __syncthreads();
        for (int q = tid; q < NQ; q += 512) {
            unsigned lc = min(lcnt[q], (unsigned)LCAP);
            pcnt[(bid << 10) + q] = lc;
            uint4 a = *(uint4*)&lbuf[q * LCAP];
            uint4 b = *(uint4*)&lbuf[q * LCAP + 4];
            long base = ((long)(bid << 10) + q) * LCAP;
            *(uint4*)&pool[base] = a;          // garbage beyond lc never read
            *(uint4*)&pool[base + 4] = b;
        }
    }
}

// ---------------- 32nd-smallest sample key -> widened threshold
__global__ __launch_bounds__(256) void k_sel(const unsigned short* __restrict__ keys,
                                             const float* __restrict__ Qm,
                                             const float* __restrict__ x2maxf,
                                             float* __restrict__ tqw,
                                             float* __restrict__ q2g) {
    int q = blockIdx.x, tid = threadIdx.x;
    unsigned short mk[32];
#pragma unroll
    for (int m = 0; m < 32; m++) mk[m] = keys[(long)q * SAMPLES + tid + 256 * m];
    __shared__ float q2s_;
    __shared__ int cnt;
    if (tid < 64) {
        float v = Qm[(long)q * 64 + tid];
        float p = v * v;
#pragma unroll
        for (int d = 1; d < 64; d <<= 1) p += __shfl_xor(p, d);
        if (tid == 0) q2s_ = p;
    }
    unsigned lo = 0, hi = 65535;
    for (int it = 0; it < 16; ++it) {
        __syncthreads();
        if (tid == 0) cnt = 0;
        __syncthreads();
        unsigned mid = (lo + hi) >> 1;
        int c = 0;
#pragma unroll
        for (int m = 0; m < 32; m++) c += (mk[m] <= mid) ? 1 : 0;
#pragma unroll
        for (int d = 1; d < 64; d <<= 1) c += __shfl_xor(c, d);
        if ((tid & 63) == 0) atomicAdd(&cnt, c);
        __syncthreads();
        if (cnt >= KSEL) hi = mid; else lo = mid + 1;
    }
    if (tid == 0) {
        unsigned vv = hi + 2u; if (vv > 65535u) vv = 65535u;
        float t = funmap(vv << 16);
        float q2 = q2s_;
        tqw[q] = t + 0.0314f * sqrtf(q2 * (*x2maxf)) + 0.2f;
        q2g[q] = q2;
    }
}

// ---------------- approx-cut -> exact re-rank survivors -> vote -> argmax
__global__ __launch_bounds__(256) void k_merge(const float* __restrict__ Qm,
                                               const float* __restrict__ X,
                                               const float* __restrict__ x2,
                                               const int* __restrict__ labels,
                                               const unsigned* __restrict__ pcnt,
                                               const unsigned* __restrict__ pool,
                                               const unsigned* __restrict__ ovfcnt,
                                               const uint2* __restrict__ ovf,
                                               const float* __restrict__ q2g,
                                               const float* __restrict__ x2maxf,
                                               int* __restrict__ out) {
    int q = blockIdx.x, tid = threadIdx.x;
    __shared__ unsigned short eK[TOTC];
    __shared__ int eR[TOTC];
    __shared__ int sR[MAXS];
    __shared__ float sKey[MAXS];
    __shared__ int sLab[MAXS];
    __shared__ float qs[64];
    __shared__ int tot, cnt, ns, nw, nt;
    __shared__ unsigned cutS;
    __shared__ float wKey[34];
    __shared__ int wLab[34];
    __shared__ int tIdx[64];
    __shared__ int tLab[64];

    if (tid == 0) { tot = 0; ns = 0; nw = 0; nt = 0; }
    if (tid < 64) qs[tid] = Qm[(long)q * 64 + tid];
    __syncthreads();

    // gather from block-exclusive pools
    for (int b = tid; b < NBLK0; b += 256) {
        unsigned lc = pcnt[(b << 10) + q];
        if (lc) {
            long base = ((long)(b << 10) + q) * LCAP;
            uint4 a = *(const uint4*)&pool[base];
            uint4 bb = *(const uint4*)&pool[base + 4];
            int p = atomicAdd(&tot, (int)lc);
            int rbase = b * CHROWS2;
#pragma unroll
            for (int i = 0; i < LCAP; i++) {
                unsigned e = (i == 0) ? a.x : (i == 1) ? a.y : (i == 2) ? a.z :
                             (i == 3) ? a.w : (i == 4) ? bb.x : (i == 5) ? bb.y :
                             (i == 6) ? bb.z : bb.w;
                int p2 = p + i;
                if ((unsigned)i < lc && p2 < TOTC) {
                    eK[p2] = (unsigned short)(e >> 9);
                    eR[p2] = rbase + (int)(e & 511u);
                }
            }
        }
    }
    int ov = min((int)ovfcnt[q], OVFCAP);
    for (int i = tid; i < ov; i += 256) {
        uint2 e = ovf[q * OVFCAP + i];
        int p = atomicAdd(&tot, 1);
        if (p < TOTC) { eK[p] = (unsigned short)e.x; eR[p] = (int)e.y; }
    }
    __syncthreads();
    int T = min(tot, TOTC);

    // bisect approx u16 keys for the 32nd smallest
    unsigned short mk[16];
#pragma unroll
    for (int m = 0; m < 16; m++) { int i = tid + (m << 8); mk[m] = (i < T) ? eK[i] : (unsigned short)0xFFFFu; }
    unsigned lo = 0, hi = 65535;
    for (int it = 0; it < 16; ++it) {
        __syncthreads();
        if (tid == 0) cnt = 0;
        __syncthreads();
        unsigned mid = (lo + hi) >> 1;
        int c = 0;
#pragma unroll
        for (int m = 0; m < 16; m++) c += (mk[m] <= mid) ? 1 : 0;
#pragma unroll
        for (int d = 1; d < 64; d <<= 1) c += __shfl_xor(c, d);
        if ((tid & 63) == 0) atomicAdd(&cnt, c);
        __syncthreads();
        if (cnt >= KSEL) hi = mid; else lo = mid + 1;
    }
    float q2v = q2g[q];
    if (tid == 0) {
        unsigned vv = min(hi + 1u, 65535u);
        float tf = funmap(vv << 16);
        float err = 0.0314f * sqrtf(q2v * (*x2maxf)) + 0.3f;   // 2x bf16 key error + margin
        cutS = min((fmap(tf + err) >> 16) + 1u, 65535u);
    }
    __syncthreads();
    unsigned cut = cutS;
    for (int i = tid; i < T; i += 256)
        if ((unsigned)eK[i] <= cut) { int p = atomicAdd(&ns, 1); if (p < MAXS) sR[p] = eR[i]; }
    __syncthreads();
    int NS = min(ns, MAXS);

    // exact fp32 re-rank of survivors
    for (int i = tid; i < NS; i += 256) {
        int row = sR[i];
        const float4* xr = (const float4*)(X + (long)row * 64);
        const float4* qr = (const float4*)qs;
        float dot = 0.f;
#pragma unroll
        for (int k4 = 0; k4 < 16; k4++) {
            float4 xv = xr[k4], qv = qr[k4];
            dot += qv.x * xv.x + qv.y * xv.y + qv.z * xv.z + qv.w * xv.w;
        }
        sKey[i] = x2[row] - 2.f * dot;
        sLab[i] = labels[row];
    }
    __syncthreads();

    // exact 32nd smallest among survivors (32-step bisection)
    unsigned uk[6];
#pragma unroll
    for (int m = 0; m < 6; m++) { int i = tid + (m << 8); uk[m] = (i < NS) ? fmap(sKey[i]) : 0xFFFFFFFFu; }
    unsigned lo2 = 0u, hi2 = 0xFFFFFFFFu;
    for (int it = 0; it < 32; ++it) {
        __syncthreads();
        if (tid == 0) cnt = 0;
        __syncthreads();
        unsigned mid = lo2 + ((hi2 - lo2) >> 1);
        int c = 0;
#pragma unroll
        for (int m = 0; m < 6; m++) c += (uk[m] <= mid) ? 1 : 0;
#pragma unroll
        for (int d = 1; d < 64; d <<= 1) c += __shfl_xor(c, d);
        if ((tid & 63) == 0) atomicAdd(&cnt, c);
        __syncthreads();
        if (cnt >= KSEL) hi2 = mid; else lo2 = mid + 1;
    }
    unsigned T32 = hi2;   // count(<T32) <= 31, count(<=T32) >= 32

#pragma unroll
    for (int m = 0; m < 6; m++) {
        int i = tid + (m << 8);
        if (i < NS) {
            if (uk[m] < T32) {
                int p = atomicAdd(&nw, 1);
                if (p < 34) { wKey[p] = sKey[i]; wLab[p] = sLab[i]; }
            } else if (uk[m] == T32) {
                int p = atomicAdd(&nt, 1);
                if (p < 64) { tIdx[p] = sR[i]; tLab[p] = sLab[i]; }
            }
        }
    }
    __syncthreads();

    if (tid == 0) {
        float votes[NCLS] = {0.f, 0.f, 0.f, 0.f, 0.f, 0.f, 0.f, 0.f, 0.f, 0.f};
        int NW = min(nw, 32);
        for (int i = 0; i < NW; i++) {
            float dist = q2v + wKey[i];
            if (dist < 0.f) dist = 0.f;
            if (dist == 0.f) dist = 0.1f;
            votes[wLab[i]] += 1.f / dist;
        }
        int need = KSEL - NW;
        int NT = min(nt, 64);
        float tkey = funmap(T32);
        float dist = q2v + tkey;
        if (dist < 0.f) dist = 0.f;
        if (dist == 0.f) dist = 0.1f;
        float twgt = 1.f / dist;
        for (int t = 0; t < need && t < NT; t++) {   // ties: smallest index first
            int best = -1, bi = 0x7FFFFFFF;
            for (int u = 0; u < NT; u++)
                if (tIdx[u] < bi) { bi = tIdx[u]; best = u; }
            if (best < 0) break;
            votes[tLab[best]] += twgt;
            tIdx[best] = 0x7FFFFFFF;
        }
        float bv = votes[0];
        int bc = 0;
#pragma unroll
        for (int c = 1; c < NCLS; c++)
            if (votes[c] > bv) { bv = votes[c]; bc = c; }
        out[q] = bc;
    }
}

extern "C" void kernel_launch(void* const* d_in, const int* in_sizes, int n_in,
                              void* d_out, int out_size, void* d_ws, size_t ws_size,
                              hipStream_t stream) {
    const float* Qm = (const float*)d_in[0];
    const float* X = (const float*)d_in[1];
    const int* labels = (const int*)d_in[2];
    char* ws = (char*)d_ws;
    // ws layout (end = 47,527,488 B; R5/R6 proved ws_size >= 52,017,408):
    // [0,800000)            x2     float[200000]
    // [800000,804096)       tqw    float[1024]
    // [804096,808192)       q2g    float[1024]
    // [808192,808196)       x2maxf float
    // [808256,820756)       bmax   float[3125]
    // [820800,2917952)      pcnt   u32[512*1024]
    // [2917952,2922048)     ovfcnt u32[1024]
    // [2922048,5019200)     ovf    uint2[1024*256]
    // [5019200,21796416)    keys u16[1024*8192] ALIASED WITH pool u32[512*1024*8]
    // [21796416,47396416)   Xb bf16[200000*64]
    // [47396416,47527488)   Qb bf16[1024*64]
    float* x2 = (float*)(ws + 0);
    float* tqw = (float*)(ws + 800000);
    float* q2g = (float*)(ws + 804096);
    float* x2maxf = (float*)(ws + 808192);
    float* bmax = (float*)(ws + 808256);
    unsigned* pcnt = (unsigned*)(ws + 820800);
    unsigned* ovfcnt = (unsigned*)(ws + 2917952);
    uint2* ovf = (uint2*)(ws + 2922048);
    unsigned short* keys = (unsigned short*)(ws + 5019200);
    unsigned* pool = (unsigned*)(ws + 5019200);
    short* Xb = (short*)(ws + 21796416);
    short* Qb = (short*)(ws + 47396416);
    int* out = (int*)d_out;

    hipMemsetAsync(ovfcnt, 0, 4096, stream);
    k_prep<<<NPB, 512, 0, stream>>>(X, x2, bmax, Xb);
    k_max<<<1, 256, 0, stream>>>(bmax, x2maxf);
    k_cvt<<<32, 256, 0, stream>>>(Qm, Qb);
    k_dist<1><<<SAMPLES / 128, 512, 0, stream>>>(Xb, Qb, x2, tqw, pcnt, pool, ovfcnt, ovf, keys);
    k_sel<<<NQ, 256, 0, stream>>>(keys, Qm, x2maxf, tqw, q2g);
    k_dist<0><<<NBLK0, 512, 0, stream>>>(Xb, Qb, x2, tqw, pcnt, pool, ovfcnt, ovf, keys);
    k_merge<<<NQ, 256, 0, stream>>>(Qm, X, x2, labels, pcnt, pool, ovfcnt, ovf, q2g, x2maxf, out);
}

// Round 8
// 244.632 us; speedup vs baseline: 2.4461x; 1.2378x over previous
//
#include <hip/hip_runtime.h>
#include <hip/hip_bf16.h>
#include <hip/hip_fp16.h>

#define N_TRAIN 200000
#define DIMS    64
#define NQ      1024
#define KSEL    32
#define NCLS    10

#define CHROWS2 391     // rows per k_dist<0> block; 512*391 >= 200000
#define NBLK0   512     // k_dist<0> grid
#define LCAP    8       // per-(block,query) pool cap
#define OVFCAP  256     // per-query overflow cap
#define TOTC    4096    // merge candidate cap per query
#define MAXS    1536    // merge survivor cap per query
#define SAMPLES 8192
#define SROWS   32      // sample rows per k_dist<1> block
#define NPB     3125    // k_prep blocks

typedef float f32x4 __attribute__((ext_vector_type(4)));
typedef short f16x8 __attribute__((ext_vector_type(8)));

__device__ __forceinline__ unsigned fmap(float f) {
    unsigned u = __float_as_uint(f);
    return u ^ ((u >> 31) ? 0xFFFFFFFFu : 0x80000000u);
}
__device__ __forceinline__ float funmap(unsigned m) {
    unsigned u = m ^ ((m >> 31) ? 0x80000000u : 0xFFFFFFFFu);
    return __uint_as_float(u);
}
__device__ __forceinline__ unsigned short f2h(float f) {   // RNE f32->f16 bits
    union { __half h; unsigned short u; } c;
    c.h = __float2half_rn(f);
    return c.u;
}
__device__ __forceinline__ f16x8 pack8h(float4 a, float4 b) {
    f16x8 r;
    r[0] = (short)f2h(a.x); r[1] = (short)f2h(a.y);
    r[2] = (short)f2h(a.z); r[3] = (short)f2h(a.w);
    r[4] = (short)f2h(b.x); r[5] = (short)f2h(b.y);
    r[6] = (short)f2h(b.z); r[7] = (short)f2h(b.w);
    return r;
}

// ---------------- fused: x2 = ||x||^2, per-block max, X -> f16 (one X read)
__global__ __launch_bounds__(512) void k_prep(const float* __restrict__ X,
                                              float* __restrict__ x2,
                                              float* __restrict__ bmax,
                                              short* __restrict__ Xh) {
    int T = blockIdx.x * 512 + threadIdx.x;   // 8 threads per row
    int row = T >> 3;
    int l8 = T & 7;
    const float4* xp = (const float4*)(X + (long)row * 64 + l8 * 8);
    float4 a = xp[0], b = xp[1];
    *(f16x8*)(Xh + (long)row * 64 + l8 * 8) = pack8h(a, b);
    float p = a.x * a.x + a.y * a.y + a.z * a.z + a.w * a.w +
              b.x * b.x + b.y * b.y + b.z * b.z + b.w * b.w;
    p += __shfl_xor(p, 1);
    p += __shfl_xor(p, 2);
    p += __shfl_xor(p, 4);
    if (l8 == 0) x2[row] = p;
    float m = p;
    m = fmaxf(m, __shfl_xor(m, 8));
    m = fmaxf(m, __shfl_xor(m, 16));
    m = fmaxf(m, __shfl_xor(m, 32));
    __shared__ float wm[8];
    if ((threadIdx.x & 63) == 0) wm[threadIdx.x >> 6] = m;
    __syncthreads();
    if (threadIdx.x == 0) {
        float r = wm[0];
#pragma unroll
        for (int i = 1; i < 8; i++) r = fmaxf(r, wm[i]);
        bmax[blockIdx.x] = r;
    }
}

__global__ __launch_bounds__(256) void k_max(const float* __restrict__ bmax,
                                             float* __restrict__ x2maxf) {
    float m = -1e30f;
    for (int i = threadIdx.x; i < NPB; i += 256) m = fmaxf(m, bmax[i]);
#pragma unroll
    for (int d = 1; d < 64; d <<= 1) m = fmaxf(m, __shfl_xor(m, d));
    __shared__ float wm[4];
    if ((threadIdx.x & 63) == 0) wm[threadIdx.x >> 6] = m;
    __syncthreads();
    if (threadIdx.x == 0)
        *x2maxf = fmaxf(fmaxf(wm[0], wm[1]), fmaxf(wm[2], wm[3]));
}

// ---------------- Q f32 -> f16
__global__ __launch_bounds__(256) void k_cvt(const float* __restrict__ src,
                                             short* __restrict__ dst) {
    long c = (long)blockIdx.x * 256 + threadIdx.x;
    const float4* xp = (const float4*)(src + c * 8);
    float4 a = xp[0], b = xp[1];
    *(f16x8*)(dst + c * 8) = pack8h(a, b);
}

// ================================================================ k_dist
// 512 threads = 8 waves; wave w owns query tile w (128 queries, A-frags in reg).
// NO LDS staging: B-fragments load straight from global (waves share via L1).
// Barrier-free main loop.
// MODE 1: 256 blocks x 32 sample rows -> packed u16 keys (q-major).
// MODE 0: 512 blocks x 391 rows -> LDS candidate pools, coalesced flush.
template<int MODE>
__global__ __launch_bounds__(512) void k_dist(
    const short* __restrict__ Xh, const short* __restrict__ Qh,
    const float* __restrict__ x2, const float* __restrict__ tqw,
    unsigned* __restrict__ pcnt, unsigned* __restrict__ pool,
    unsigned* __restrict__ ovfcnt, uint2* __restrict__ ovf,
    unsigned short* __restrict__ keys) {
    int bid = blockIdx.x;
    int tid = threadIdx.x;
    int qt = tid >> 6;          // wave = query tile 0..7
    int lane = tid & 63;
    int lr = lane & 15;
    int lk = lane >> 4;

    __shared__ unsigned lcnt[MODE == 0 ? NQ : 1];
    __shared__ unsigned lbuf[MODE == 0 ? NQ * LCAP : 1];

    int r0 = MODE ? (bid * SROWS) : bid * CHROWS2;
    int rowEnd = MODE ? (r0 + SROWS) : min(r0 + CHROWS2, N_TRAIN);

    if (MODE == 0) {
        lcnt[tid] = 0u;
        lcnt[tid + 512] = 0u;
        __syncthreads();
    }

    // A fragments: lane holds Q[qt*128+qi*16+lr][lk*8+j] per half
    f16x8 afr[8][2];
#pragma unroll
    for (int qi = 0; qi < 8; qi++) {
        const short* qp = Qh + (long)((qt << 7) + (qi << 4) + lr) * 64 + (lk << 3);
        afr[qi][0] = *(const f16x8*)qp;
        afr[qi][1] = *(const f16x8*)(qp + 32);
    }
    float htq[8];
    if (MODE == 0) {
#pragma unroll
        for (int qi = 0; qi < 8; qi++) {
            float4 t4 = *(const float4*)(tqw + (qt << 7) + (qi << 4) + (lk << 2));
            htq[qi] = 0.5f * fmaxf(fmaxf(t4.x, t4.y), fmaxf(t4.z, t4.w));
        }
    }

    for (int base = r0; base < rowEnd; base += 16) {
        int row = base + lr;
        bool valid = row < rowEnd;
        int rowc = valid ? row : (rowEnd - 1);
        const short* xp = Xh + (long)rowc * 64 + (lk << 3);
        f16x8 b0 = *(const f16x8*)xp;
        f16x8 b1 = *(const f16x8*)(xp + 32);
        float x2c = valid ? x2[rowc] : 1e30f;
        float hx = 0.5f * x2c;

#pragma unroll
        for (int qi = 0; qi < 8; qi++) {
            f32x4 acc = {0.f, 0.f, 0.f, 0.f};
            acc = __builtin_amdgcn_mfma_f32_16x16x32_f16(afr[qi][0], b0, acc, 0, 0, 0);
            acc = __builtin_amdgcn_mfma_f32_16x16x32_f16(afr[qi][1], b1, acc, 0, 0, 0);
            if (MODE == 1) {
#pragma unroll
                for (int r4 = 0; r4 < 4; r4++) {
                    unsigned k16 = fmap(x2c - 2.f * acc[r4]) >> 16;
                    unsigned o = (unsigned)__shfl_xor((int)k16, 1);
                    unsigned v2 = k16 | (o << 16);                  // rows lr,lr+1
                    unsigned p2 = (unsigned)__shfl_xor((int)v2, 2); // rows lr+2,lr+3
                    if ((lr & 3) == 0) {
                        int qg = (qt << 7) + (qi << 4) + (lk << 2) + r4;
                        *(uint2*)(&keys[(long)qg * SAMPLES + row]) = make_uint2(v2, p2);
                    }
                }
            } else {
                float mx = fmaxf(fmaxf(acc[0], acc[1]), fmaxf(acc[2], acc[3]));
                if (valid && mx + htq[qi] >= hx) {     // sound quick reject
                    float4 t4 = *(const float4*)(tqw + (qt << 7) + (qi << 4) + (lk << 2));
                    float tq4[4] = {t4.x, t4.y, t4.z, t4.w};
#pragma unroll
                    for (int r4 = 0; r4 < 4; r4++) {
                        if (acc[r4] + 0.5f * tq4[r4] >= hx) {
                            int qg = (qt << 7) + (qi << 4) + (lk << 2) + r4;
                            // 23-bit approx key + 9-bit local row
                            unsigned entry = (fmap(x2c - 2.f * acc[r4]) & 0xFFFFFE00u) |
                                             (unsigned)(row - r0);
                            unsigned slot = atomicAdd(&lcnt[qg], 1u);
                            if (slot < LCAP) {
                                lbuf[qg * LCAP + slot] = entry;
                            } else {   // rare overflow: per-query global pool
                                unsigned o = atomicAdd(&ovfcnt[qg], 1u);
                                if (o < OVFCAP)
                                    ovf[qg * OVFCAP + o] =
                                        make_uint2(entry >> 9, (unsigned)row);
                            }
                        }
                    }
                }
            }
        }
    }

    if (MODE == 0) {   // coalesced flush: no global atomics, dense 32B per (bid,q)
        __syncthreads();
        for (int q = tid; q < NQ; q += 512) {
            unsigned lc = min(lcnt[q], (unsigned)LCAP);
            pcnt[(bid << 10) + q] = lc;
            uint4 a = *(uint4*)&lbuf[q * LCAP];
            uint4 b = *(uint4*)&lbuf[q * LCAP + 4];
            long base = ((long)(bid << 10) + q) * LCAP;
            *(uint4*)&pool[base] = a;          // garbage beyond lc never read
            *(uint4*)&pool[base + 4] = b;
        }
    }
}

// ---------------- 32nd-smallest sample key -> widened threshold (f16 bound)
__global__ __launch_bounds__(256) void k_sel(const unsigned short* __restrict__ keys,
                                             const float* __restrict__ Qm,
                                             const float* __restrict__ x2maxf,
                                             float* __restrict__ tqw,
                                             float* __restrict__ q2g) {
    int q = blockIdx.x, tid = threadIdx.x;
    unsigned short mk[32];
#pragma unroll
    for (int m = 0; m < 32; m++) mk[m] = keys[(long)q * SAMPLES + tid + 256 * m];
    __shared__ float q2s_;
    __shared__ int cnt;
    if (tid < 64) {
        float v = Qm[(long)q * 64 + tid];
        float p = v * v;
#pragma unroll
        for (int d = 1; d < 64; d <<= 1) p += __shfl_xor(p, d);
        if (tid == 0) q2s_ = p;
    }
    unsigned lo = 0, hi = 65535;
    for (int it = 0; it < 16; ++it) {
        __syncthreads();
        if (tid == 0) cnt = 0;
        __syncthreads();
        unsigned mid = (lo + hi) >> 1;
        int c = 0;
#pragma unroll
        for (int m = 0; m < 32; m++) c += (mk[m] <= mid) ? 1 : 0;
#pragma unroll
        for (int d = 1; d < 64; d <<= 1) c += __shfl_xor(c, d);
        if ((tid & 63) == 0) atomicAdd(&cnt, c);
        __syncthreads();
        if (cnt >= KSEL) hi = mid; else lo = mid + 1;
    }
    if (tid == 0) {
        unsigned vv = hi + 2u; if (vv > 65535u) vv = 65535u;
        float t = funmap(vv << 16);
        float q2 = q2s_;
        // widen: 2x f16 dot-error bound (2^-10 ||q|| ||x||max total) + margin
        tqw[q] = t + 0.004f * sqrtf(q2 * (*x2maxf)) + 0.1f;
        q2g[q] = q2;
    }
}

// ---------------- approx-cut (23-bit) -> exact re-rank survivors -> vote
__global__ __launch_bounds__(256) void k_merge(const float* __restrict__ Qm,
                                               const float* __restrict__ X,
                                               const float* __restrict__ x2,
                                               const int* __restrict__ labels,
                                               const unsigned* __restrict__ pcnt,
                                               const unsigned* __restrict__ pool,
                                               const unsigned* __restrict__ ovfcnt,
                                               const uint2* __restrict__ ovf,
                                               const float* __restrict__ q2g,
                                               const float* __restrict__ x2maxf,
                                               int* __restrict__ out) {
    int q = blockIdx.x, tid = threadIdx.x;
    __shared__ unsigned eK[TOTC];        // 23-bit approx keys
    __shared__ int eR[TOTC];
    __shared__ int sR[MAXS];
    __shared__ float sKey[MAXS];
    __shared__ int sLab[MAXS];
    __shared__ float qs[64];
    __shared__ int tot, cnt, ns, nw, nt;
    __shared__ unsigned cutS;
    __shared__ float wKey[34];
    __shared__ int wLab[34];
    __shared__ int tIdx[64];
    __shared__ int tLab[64];

    if (tid == 0) { tot = 0; ns = 0; nw = 0; nt = 0; }
    if (tid < 64) qs[tid] = Qm[(long)q * 64 + tid];
    __syncthreads();

    // gather from block-exclusive pools
    for (int b = tid; b < NBLK0; b += 256) {
        unsigned lc = pcnt[(b << 10) + q];
        if (lc) {
            long base = ((long)(b << 10) + q) * LCAP;
            uint4 a = *(const uint4*)&pool[base];
            uint4 bb = *(const uint4*)&pool[base + 4];
            int p = atomicAdd(&tot, (int)lc);
            int rbase = b * CHROWS2;
#pragma unroll
            for (int i = 0; i < LCAP; i++) {
                unsigned e = (i == 0) ? a.x : (i == 1) ? a.y : (i == 2) ? a.z :
                             (i == 3) ? a.w : (i == 4) ? bb.x : (i == 5) ? bb.y :
                             (i == 6) ? bb.z : bb.w;
                int p2 = p + i;
                if ((unsigned)i < lc && p2 < TOTC) {
                    eK[p2] = e >> 9;
                    eR[p2] = rbase + (int)(e & 511u);
                }
            }
        }
    }
    int ov = min((int)ovfcnt[q], OVFCAP);
    for (int i = tid; i < ov; i += 256) {
        uint2 e = ovf[q * OVFCAP + i];
        int p = atomicAdd(&tot, 1);
        if (p < TOTC) { eK[p] = e.x; eR[p] = (int)e.y; }
    }
    __syncthreads();
    int T = min(tot, TOTC);

    // bisect 23-bit approx keys for the 32nd smallest
    unsigned mk[16];
#pragma unroll
    for (int m = 0; m < 16; m++) { int i = tid + (m << 8); mk[m] = (i < T) ? eK[i] : 0xFFFFFFFFu; }
    unsigned lo = 0, hi = 0x7FFFFFu;
    for (int it = 0; it < 23; ++it) {
        __syncthreads();
        if (tid == 0) cnt = 0;
        __syncthreads();
        unsigned mid = (lo + hi) >> 1;
        int c = 0;
#pragma unroll
        for (int m = 0; m < 16; m++) c += (mk[m] <= mid) ? 1 : 0;
#pragma unroll
        for (int d = 1; d < 64; d <<= 1) c += __shfl_xor(c, d);
        if ((tid & 63) == 0) atomicAdd(&cnt, c);
        __syncthreads();
        if (cnt >= KSEL) hi = mid; else lo = mid + 1;
    }
    float q2v = q2g[q];
    if (tid == 0) {
        unsigned vv = min(hi + 1u, 0x7FFFFFu);
        float tf = funmap(vv << 9);
        float err = 0.004f * sqrtf(q2v * (*x2maxf)) + 0.1f;   // 2x f16 key error + margin
        cutS = min((fmap(tf + err) >> 9) + 1u, 0x7FFFFFu);
    }
    __syncthreads();
    unsigned cut = cutS;
    for (int i = tid; i < T; i += 256)
        if (eK[i] <= cut) { int p = atomicAdd(&ns, 1); if (p < MAXS) sR[p] = eR[i]; }
    __syncthreads();
    int NS = min(ns, MAXS);

    // exact fp32 re-rank of survivors
    for (int i = tid; i < NS; i += 256) {
        int row = sR[i];
        const float4* xr = (const float4*)(X + (long)row * 64);
        const float4* qr = (const float4*)qs;
        float dot = 0.f;
#pragma unroll
        for (int k4 = 0; k4 < 16; k4++) {
            float4 xv = xr[k4], qv = qr[k4];
            dot += qv.x * xv.x + qv.y * xv.y + qv.z * xv.z + qv.w * xv.w;
        }
        sKey[i] = x2[row] - 2.f * dot;
        sLab[i] = labels[row];
    }
    __syncthreads();

    // exact 32nd smallest among survivors (32-step bisection)
    unsigned uk[6];
#pragma unroll
    for (int m = 0; m < 6; m++) { int i = tid + (m << 8); uk[m] = (i < NS) ? fmap(sKey[i]) : 0xFFFFFFFFu; }
    unsigned lo2 = 0u, hi2 = 0xFFFFFFFFu;
    for (int it = 0; it < 32; ++it) {
        __syncthreads();
        if (tid == 0) cnt = 0;
        __syncthreads();
        unsigned mid = lo2 + ((hi2 - lo2) >> 1);
        int c = 0;
#pragma unroll
        for (int m = 0; m < 6; m++) c += (uk[m] <= mid) ? 1 : 0;
#pragma unroll
        for (int d = 1; d < 64; d <<= 1) c += __shfl_xor(c, d);
        if ((tid & 63) == 0) atomicAdd(&cnt, c);
        __syncthreads();
        if (cnt >= KSEL) hi2 = mid; else lo2 = mid + 1;
    }
    unsigned T32 = hi2;   // count(<T32) <= 31, count(<=T32) >= 32

#pragma unroll
    for (int m = 0; m < 6; m++) {
        int i = tid + (m << 8);
        if (i < NS) {
            if (uk[m] < T32) {
                int p = atomicAdd(&nw, 1);
                if (p < 34) { wKey[p] = sKey[i]; wLab[p] = sLab[i]; }
            } else if (uk[m] == T32) {
                int p = atomicAdd(&nt, 1);
                if (p < 64) { tIdx[p] = sR[i]; tLab[p] = sLab[i]; }
            }
        }
    }
    __syncthreads();

    if (tid == 0) {
        float votes[NCLS] = {0.f, 0.f, 0.f, 0.f, 0.f, 0.f, 0.f, 0.f, 0.f, 0.f};
        int NW = min(nw, 32);
        for (int i = 0; i < NW; i++) {
            float dist = q2v + wKey[i];
            if (dist < 0.f) dist = 0.f;
            if (dist == 0.f) dist = 0.1f;
            votes[wLab[i]] += 1.f / dist;
        }
        int need = KSEL - NW;
        int NT = min(nt, 64);
        float tkey = funmap(T32);
        float dist = q2v + tkey;
        if (dist < 0.f) dist = 0.f;
        if (dist == 0.f) dist = 0.1f;
        float twgt = 1.f / dist;
        for (int t = 0; t < need && t < NT; t++) {   // ties: smallest index first
            int best = -1, bi = 0x7FFFFFFF;
            for (int u = 0; u < NT; u++)
                if (tIdx[u] < bi) { bi = tIdx[u]; best = u; }
            if (best < 0) break;
            votes[tLab[best]] += twgt;
            tIdx[best] = 0x7FFFFFFF;
        }
        float bv = votes[0];
        int bc = 0;
#pragma unroll
        for (int c = 1; c < NCLS; c++)
            if (votes[c] > bv) { bv = votes[c]; bc = c; }
        out[q] = bc;
    }
}

extern "C" void kernel_launch(void* const* d_in, const int* in_sizes, int n_in,
                              void* d_out, int out_size, void* d_ws, size_t ws_size,
                              hipStream_t stream) {
    const float* Qm = (const float*)d_in[0];
    const float* X = (const float*)d_in[1];
    const int* labels = (const int*)d_in[2];
    char* ws = (char*)d_ws;
    // ws layout (end = 47,527,488 B; proven ws_size >= 52,017,408):
    // [0,800000)            x2     float[200000]
    // [800000,804096)       tqw    float[1024]
    // [804096,808192)       q2g    float[1024]
    // [808192,808196)       x2maxf float
    // [808256,820756)       bmax   float[3125]
    // [820800,2917952)      pcnt   u32[512*1024]
    // [2917952,2922048)     ovfcnt u32[1024]
    // [2922048,5019200)     ovf    uint2[1024*256]
    // [5019200,21796416)    keys u16[1024*8192] ALIASED WITH pool u32[512*1024*8]
    // [21796416,47396416)   Xh f16[200000*64]
    // [47396416,47527488)   Qh f16[1024*64]
    float* x2 = (float*)(ws + 0);
    float* tqw = (float*)(ws + 800000);
    float* q2g = (float*)(ws + 804096);
    float* x2maxf = (float*)(ws + 808192);
    float* bmax = (float*)(ws + 808256);
    unsigned* pcnt = (unsigned*)(ws + 820800);
    unsigned* ovfcnt = (unsigned*)(ws + 2917952);
    uint2* ovf = (uint2*)(ws + 2922048);
    unsigned short* keys = (unsigned short*)(ws + 5019200);
    unsigned* pool = (unsigned*)(ws + 5019200);
    short* Xh = (short*)(ws + 21796416);
    short* Qh = (short*)(ws + 47396416);
    int* out = (int*)d_out;

    hipMemsetAsync(ovfcnt, 0, 4096, stream);
    k_prep<<<NPB, 512, 0, stream>>>(X, x2, bmax, Xh);
    k_max<<<1, 256, 0, stream>>>(bmax, x2maxf);
    k_cvt<<<32, 256, 0, stream>>>(Qm, Qh);
    k_dist<1><<<SAMPLES / SROWS, 512, 0, stream>>>(Xh, Qh, x2, tqw, pcnt, pool, ovfcnt, ovf, keys);
    k_sel<<<NQ, 256, 0, stream>>>(keys, Qm, x2maxf, tqw, q2g);
    k_dist<0><<<NBLK0, 512, 0, stream>>>(Xh, Qh, x2, tqw, pcnt, pool, ovfcnt, ovf, keys);
    k_merge<<<NQ, 256, 0, stream>>>(Qm, X, x2, labels, pcnt, pool, ovfcnt, ovf, q2g, x2maxf, out);
}